// Round 7
// baseline (372.367 us; speedup 1.0000x reference)
//
#include <hip/hip_runtime.h>
#include <math.h>

#define HWDIM 256
#define CH 32
#define NB 8
#define TILE 16
#define NLOC (NB*HWDIM*HWDIM)   /* 524288 locations */
#define R_CLAMP 4.9517189f      /* artanh(0.9999) */
#define MAXN 0.9999f
#define BN_EPS 1e-5f
#define EPSF 1e-5f
#define TPB 2                   /* tiles per conv block */
#define GRIDC 1024              /* conv blocks = 2048 tiles / TPB; 4 per CU */
#define OST 264                 /* out_kernel LDS row stride (floats) */

typedef __attribute__((ext_vector_type(8))) _Float16 half8;
typedef __attribute__((ext_vector_type(4))) _Float16 half4;
typedef __attribute__((ext_vector_type(4))) float floatx4;

__device__ __forceinline__ float artanh_fast(float n) {
    float t = fminf(n, 1.0f - 1e-5f);
    // artanh(t) = 0.5*ln((1+t)/(1-t)); one v_log + fast divide; ~1e-6 rel err << fp16 path
    return 0.5f * __logf(__fdividef(1.0f + t, 1.0f - t));
}

// pack both weight tensors to fp16: w[co][ci][3][3] -> wp[((o*4+g)*32+co)*8+j], ci=g*8+j
// Also zeroes the BN accumulators/counters for both convs (workspace is poisoned
// between iterations; these stores are visible to conv1/conv2 via dispatch boundary).
__global__ __launch_bounds__(256) void wprep_kernel(
    const float* __restrict__ w1, const float* __restrict__ w2,
    _Float16* __restrict__ wp1, _Float16* __restrict__ wp2,
    float* __restrict__ gstatA, unsigned* __restrict__ ctrA,
    float* __restrict__ gstatB, unsigned* __restrict__ ctrB)
{
    int idx = blockIdx.x * 256 + threadIdx.x;
    if (blockIdx.x == 0) {
        int tid = threadIdx.x;
        if (tid < 64) { gstatA[tid] = 0.f; gstatB[tid] = 0.f; }
        if (tid == 64) *ctrA = 0u;
        if (tid == 65) *ctrB = 0u;
    }
    if (idx >= 2*CH*CH*9) return;
    int s = idx >= CH*CH*9;
    int id = idx - s*(CH*CH*9);
    const float* w = s ? w2 : w1;
    _Float16* wp = s ? wp2 : wp1;
    int j  = id & 7;
    int r  = id >> 3;
    int co = r & 31;
    int og = r >> 5;
    int g  = og & 3;
    int o  = og >> 2;
    int ci = g*8 + j;
    wp[id] = (_Float16)w[(co*CH + ci)*9 + o];
}

// Multi-tile conv with fused BN-stat finalize (last-block pattern).
// STAGE 1: src = x fp32 NCHW, staging applies logmap0.
// STAGE 2: src = t1 fp16 channel-minor, staging applies bn1 + clampnorm + relu.
// Staging uses the round-0 loop form (one transient v[32] live at a time -> 56 VGPR
// there; round-6's dual inlined copies software-pipelined to 112 VGPR. Lesson: keep
// the per-loc bodies in ONE sequential loop, #pragma unroll 1).
template<int STAGE>
__global__ __launch_bounds__(256) void conv_mfma_kernel(
    const void* __restrict__ srcv,
    const _Float16* __restrict__ wp,      // [9][4][32co][8ci] fp16
    const float* __restrict__ bias,
    const float* __restrict__ scsh_in,    // [2*CH] bn1 scale/shift (STAGE 2 only)
    _Float16* __restrict__ dst,
    float* __restrict__ gstat,            // [64]: sums ch0..31, sumsq ch0..31
    unsigned* __restrict__ ctr,
    const float* __restrict__ gamma, const float* __restrict__ beta,
    float* __restrict__ scsh_out)         // [2*CH] written by last block
{
    __shared__ _Float16 ah[10368];        // [18y][4g][18x][8ci] = 20736 B
    __shared__ float red[4][64];
    __shared__ bool lastf;

    const int tid = threadIdx.x;
    const int b   = blockIdx.x;           // 0..1023
    const int bz  = b & 7;                // image per XCD
    const int tb  = b >> 3;               // 0..127
    const int by  = tb >> 3;              // 0..15
    const int bx0 = (tb & 7) * TPB;       // 0,2,..,14
    const int h0  = by*TILE - 1;
    const int wbase = bx0*TILE - 1;

    const int lane = tid & 63, wave = tid >> 6;
    const int xx = lane & 15, q = lane >> 4;

    float bs[8];
    #pragma unroll
    for (int r = 0; r < 4; r++) { bs[r] = bias[q*4+r]; bs[4+r] = bias[q*4+r+16]; }
    float sv[8], qv[8];
    #pragma unroll
    for (int k = 0; k < 8; k++) { sv[k] = 0.f; qv[k] = 0.f; }

    #pragma unroll 1
    for (int j = 0; j < TPB; j++) {
        const int w0 = wbase + j*TILE;
        // ---- staging: sequential per-loc loop, regs transient (round-0 form) ----
        #pragma unroll 1
        for (int loc = tid; loc < 324; loc += 256) {
            int y = loc / 18, x = loc - y*18;
            int gh = h0 + y, gw = w0 + x;
            _Float16* base = ah + ((y*4)*18 + x)*8;
            if (gh < 0 || gh >= HWDIM || gw < 0 || gw >= HWDIM) {
                half8 z = {0,0,0,0,0,0,0,0};
                #pragma unroll
                for (int g = 0; g < 4; g++) *(half8*)(base + g*144) = z;
                continue;
            }
            float v[CH]; float n2 = 0.f;
            if (STAGE == 1) {
                const float* p = (const float*)srcv + ((size_t)bz*CH << 16) + gh*HWDIM + gw;
                #pragma unroll
                for (int c = 0; c < CH; c++) { float t0 = p[(size_t)c << 16]; v[c] = t0; n2 = fmaf(t0, t0, n2); }
                float n = fmaxf(sqrtf(n2), EPSF);
                float f = __fdividef(artanh_fast(n), n);
                #pragma unroll
                for (int g = 0; g < 4; g++) {
                    half8 hv;
                    #pragma unroll
                    for (int jj = 0; jj < 8; jj++) hv[jj] = (_Float16)(v[g*8 + jj] * f);
                    *(half8*)(base + g*144) = hv;
                }
            } else {
                const _Float16* p = (const _Float16*)srcv + (((size_t)bz << 16) + gh*HWDIM + gw)*CH;
                half8 raw[4];
                #pragma unroll
                for (int k = 0; k < 4; k++) raw[k] = *(const half8*)(p + 8*k);
                #pragma unroll
                for (int c = 0; c < CH; c++) {
                    float t0 = fmaf((float)raw[c>>3][c&7], scsh_in[c], scsh_in[CH + c]);
                    v[c] = t0; n2 = fmaf(t0, t0, n2);
                }
                float n = sqrtf(n2);
                float f = (n > R_CLAMP) ? __fdividef(R_CLAMP, n) : 1.0f;
                #pragma unroll
                for (int g = 0; g < 4; g++) {
                    half8 hv;
                    #pragma unroll
                    for (int jj = 0; jj < 8; jj++) hv[jj] = (_Float16)fmaxf(v[g*8 + jj]*f, 0.0f);
                    *(half8*)(base + g*144) = hv;
                }
            }
        }
        __syncthreads();

        // ---- implicit GEMM, swapped operands: A = weights (m=co), B = acts (n=loc) ----
        floatx4 acc[4][2];
        #pragma unroll
        for (int i = 0; i < 4; i++) {
            acc[i][0] = (floatx4){0.f,0.f,0.f,0.f};
            acc[i][1] = (floatx4){0.f,0.f,0.f,0.f};
        }
        __builtin_amdgcn_s_setprio(1);
        #pragma unroll
        for (int dx = 0; dx < 3; dx++) {
            half8 af[6];
            #pragma unroll
            for (int yy = 0; yy < 6; yy++)
                af[yy] = *(const half8*)(ah + (((wave*4+yy)*4 + q)*18 + xx + dx)*8);
            #pragma unroll
            for (int dy = 0; dy < 3; dy++) {
                const int o = dy*3 + dx;
                const _Float16* wb = wp + (size_t)((o*4 + q)*32)*8;
                half8 wf0 = *(const half8*)(wb + xx*8);          // co 0..15
                half8 wf1 = *(const half8*)(wb + (xx+16)*8);     // co 16..31
                #pragma unroll
                for (int i = 0; i < 4; i++) {
                    acc[i][0] = __builtin_amdgcn_mfma_f32_16x16x32_f16(wf0, af[i+dy], acc[i][0], 0,0,0);
                    acc[i][1] = __builtin_amdgcn_mfma_f32_16x16x32_f16(wf1, af[i+dy], acc[i][1], 0,0,0);
                }
            }
        }
        __builtin_amdgcn_s_setprio(0);

        // ---- register epilogue: thread owns ch {q*4+r, q*4+r+16} of loc (y=wave*4+i, x=xx) ----
        _Float16* dp = dst + (((size_t)bz << 16) + (size_t)(by*TILE)*HWDIM + (bx0 + j)*TILE + xx)*CH + q*4;
        #pragma unroll
        for (int i = 0; i < 4; i++) {
            float n2 = 0.f;
            #pragma unroll
            for (int r = 0; r < 4; r++) {
                acc[i][0][r] += bs[r];
                acc[i][1][r] += bs[4+r];
                n2 = fmaf(acc[i][0][r], acc[i][0][r], n2);
                n2 = fmaf(acc[i][1][r], acc[i][1][r], n2);
            }
            n2 += __shfl_xor(n2, 16, 64);
            n2 += __shfl_xor(n2, 32, 64);
            float nn = sqrtf(n2);
            float f = (nn > R_CLAMP) ? __fdividef(R_CLAMP, nn) : 1.0f;
            half4 o0, o1;
            #pragma unroll
            for (int r = 0; r < 4; r++) {
                float a0 = acc[i][0][r] * f;
                float a1 = acc[i][1][r] * f;
                sv[r]   += a0; qv[r]   = fmaf(a0, a0, qv[r]);
                sv[4+r] += a1; qv[4+r] = fmaf(a1, a1, qv[4+r]);
                o0[r] = (_Float16)a0; o1[r] = (_Float16)a1;
            }
            _Float16* a = dp + (size_t)(wave*4 + i)*HWDIM*CH;
            *(half4*)(a)      = o0;
            *(half4*)(a + 16) = o1;
        }
        __syncthreads();                   // LDS safe to overwrite next iteration
    }

    // ---- BN partials: block reduce, then global atomic accumulate ----
    #pragma unroll
    for (int k = 0; k < 8; k++) {
        #pragma unroll
        for (int m = 1; m < 16; m <<= 1) {
            sv[k] += __shfl_xor(sv[k], m, 64);
            qv[k] += __shfl_xor(qv[k], m, 64);
        }
    }
    if (xx == 0) {
        #pragma unroll
        for (int r = 0; r < 4; r++) {
            red[wave][q*4+r]        = sv[r];
            red[wave][16 + q*4+r]   = sv[4+r];
            red[wave][32 + q*4+r]   = qv[r];
            red[wave][48 + q*4+r]   = qv[4+r];
        }
    }
    __syncthreads();
    if (tid < 64) {
        float s = red[0][tid] + red[1][tid] + red[2][tid] + red[3][tid];
        __hip_atomic_fetch_add(&gstat[tid], s, __ATOMIC_RELAXED, __HIP_MEMORY_SCOPE_AGENT);
    }
    __syncthreads();                       // all this block's atomics retired (vmcnt drain)
    if (tid == 0) {
        __threadfence();                   // device-scope release for our stores
        unsigned t = __hip_atomic_fetch_add(ctr, 1u, __ATOMIC_ACQ_REL, __HIP_MEMORY_SCOPE_AGENT);
        lastf = (t == (unsigned)(GRIDC - 1));
    }
    __syncthreads();
    if (lastf && tid < 32) {
        // last block: all 1024 blocks' atomics happened-before our counter acquire
        float sum = __hip_atomic_load(&gstat[tid],      __ATOMIC_RELAXED, __HIP_MEMORY_SCOPE_AGENT);
        float sq  = __hip_atomic_load(&gstat[32 + tid], __ATOMIC_RELAXED, __HIP_MEMORY_SCOPE_AGENT);
        const float NS = (float)NLOC;
        float mean = sum / NS;
        float var = fmaxf(sq / NS - mean*mean, 0.0f);
        float sc = gamma[tid] / sqrtf(var + BN_EPS);
        scsh_out[tid] = sc;                 // visible to next dispatch via kernel boundary
        scsh_out[CH + tid] = beta[tid] - mean*sc;
    }
}

// read t4 fp16 channel-minor; bn2+clampnorm+relu+expmap0+project; write fp32 NCHW
__global__ __launch_bounds__(256) void out_kernel(
    const _Float16* __restrict__ t4c, const float* __restrict__ scsh,
    float* __restrict__ out)
{
    __shared__ float outb[16*OST];
    const int w = threadIdx.x;
    const int h = blockIdx.x, n = blockIdx.y;
    const _Float16* p = t4c + (((size_t)n << 16) + (size_t)h*HWDIM + w)*CH;
    half8 raw[4];
    #pragma unroll
    for (int k = 0; k < 4; k++) raw[k] = *(const half8*)(p + 8*k);
    float u[CH]; float n2 = 0.f;
    #pragma unroll
    for (int c = 0; c < CH; c++) {
        float t = fmaf((float)raw[c>>3][c&7], scsh[c], scsh[CH+c]);
        u[c] = t; n2 = fmaf(t, t, n2);
    }
    float nn = sqrtf(n2);
    float f = (nn > R_CLAMP) ? __fdividef(R_CLAMP, nn) : 1.0f;
    float r2 = 0.f;
    #pragma unroll
    for (int c = 0; c < CH; c++) { float r = fmaxf(u[c]*f, 0.0f); u[c] = r; r2 = fmaf(r, r, r2); }
    float rn = fmaxf(sqrtf(r2), EPSF);
    // tanh(rn) = (e^{2rn}-1)/(e^{2rn}+1); rn <= ~4.95 so e^{2rn} <= ~2e4, safe in fp32
    float a = __expf(2.0f * rn);
    float th = __fdividef(a - 1.0f, a + 1.0f);
    float s = __fdividef(fminf(th, MAXN), rn);
    #pragma unroll
    for (int c = 0; c < CH; c++) u[c] *= s;

    #pragma unroll
    for (int hf = 0; hf < 2; hf++) {
        if (hf) __syncthreads();
        #pragma unroll
        for (int c = 0; c < 16; c++) outb[c*OST + w] = u[hf*16 + c];
        __syncthreads();
        int co = threadIdx.x >> 4, seg = threadIdx.x & 15;
        const float* row = outb + co*OST + seg*16;
        float* gp = out + ((size_t)(n*CH + hf*16 + co) << 16) + (size_t)h*HWDIM + seg*16;
        #pragma unroll
        for (int k = 0; k < 4; k++) *(floatx4*)(gp + 4*k) = *(const floatx4*)(row + 4*k);
    }
}

extern "C" void kernel_launch(void* const* d_in, const int* in_sizes, int n_in,
                              void* d_out, int out_size, void* d_ws, size_t ws_size,
                              hipStream_t stream)
{
    const float* x   = (const float*)d_in[0];
    const float* w1  = (const float*)d_in[1];
    const float* b1  = (const float*)d_in[2];
    const float* g1  = (const float*)d_in[3];
    const float* be1 = (const float*)d_in[4];
    const float* w2  = (const float*)d_in[5];
    const float* b2  = (const float*)d_in[6];
    const float* g2  = (const float*)d_in[7];
    const float* be2 = (const float*)d_in[8];
    float* outf = (float*)d_out;

    char* ws = (char*)d_ws;
    _Float16* wp1   = (_Float16*)ws;                       // 18432 B
    _Float16* wp2   = wp1 + 9216;                          // -> 36864
    float* gstatA   = (float*)(ws + 36864);                // 64 floats -> 37120
    unsigned* ctrA  = (unsigned*)(ws + 37120);             // -> 37184 (padded)
    float* gstatB   = (float*)(ws + 37184);                // 64 floats -> 37440
    unsigned* ctrB  = (unsigned*)(ws + 37440);             // -> 37504 (padded)
    float* scsh1    = (float*)(ws + 37504);                // 64 floats -> 37760
    float* scsh2    = (float*)(ws + 37760);                // 64 floats -> 38016
    _Float16* t1c   = (_Float16*)(ws + 38016);             // 32 MB (16B-aligned)
    _Float16* t4c   = t1c + (size_t)NLOC*CH;               // 32 MB

    wprep_kernel<<<72, 256, 0, stream>>>(w1, w2, wp1, wp2, gstatA, ctrA, gstatB, ctrB);

    conv_mfma_kernel<1><<<GRIDC, 256, 0, stream>>>(x,   wp1, b1, scsh1, t1c, gstatA, ctrA, g1, be1, scsh1);
    conv_mfma_kernel<2><<<GRIDC, 256, 0, stream>>>(t1c, wp2, b2, scsh1, t4c, gstatB, ctrB, g2, be2, scsh2);
    out_kernel<<<dim3(HWDIM, NB), 256, 0, stream>>>(t4c, scsh2, outf);
}

// Round 9
// 200.827 us; speedup vs baseline: 1.8542x; 1.8542x over previous
//
#include <hip/hip_runtime.h>
#include <math.h>

#define HWDIM 256
#define CH 32
#define NB 8
#define TILE 16
#define NLOC (NB*HWDIM*HWDIM)   /* 524288 locations */
#define R_CLAMP 4.9517189f      /* artanh(0.9999) */
#define MAXN 0.9999f
#define BN_EPS 1e-5f
#define EPSF 1e-5f
#define NBLK 2048
#define OST 264                 /* out_kernel LDS row stride (floats) */

typedef __attribute__((ext_vector_type(8))) _Float16 half8;
typedef __attribute__((ext_vector_type(4))) _Float16 half4;
typedef __attribute__((ext_vector_type(4))) float floatx4;

__device__ __forceinline__ float artanh_fast(float n) {
    float t = fminf(n, 1.0f - 1e-5f);
    // artanh(t) = 0.5*ln((1+t)/(1-t)); one v_log + fast divide; ~1e-6 rel err << fp16 path
    return 0.5f * __logf(__fdividef(1.0f + t, 1.0f - t));
}

// pack both weight tensors to fp16: w[co][ci][3][3] -> wp[((o*4+g)*32+co)*8+j], ci=g*8+j
__global__ __launch_bounds__(256) void wprep_kernel(
    const float* __restrict__ w1, const float* __restrict__ w2,
    _Float16* __restrict__ wp1, _Float16* __restrict__ wp2)
{
    int idx = blockIdx.x * 256 + threadIdx.x;
    if (idx >= 2*CH*CH*9) return;
    int s = idx >= CH*CH*9;
    int id = idx - s*(CH*CH*9);
    const float* w = s ? w2 : w1;
    _Float16* wp = s ? wp2 : wp1;
    int j  = id & 7;
    int r  = id >> 3;
    int co = r & 31;
    int og = r >> 5;
    int g  = og & 3;
    int o  = og >> 2;
    int ci = g*8 + j;
    wp[id] = (_Float16)w[(co*CH + ci)*9 + o];
}

// STAGE 1: src = x fp32 NCHW, staging transform = logmap0
// STAGE 2: src = t1 fp16 channel-minor [N*H*W][32], transform = bn1+clampnorm+relu
// dst (both stages): fp16 channel-minor [N*H*W][32]
// Round-0 structure (proven 51.8/48.8 us, VGPR 56, no spill): 1 tile/block, 2048 blocks,
// sequential loop-form staging (one transient v[32] at a time — any restructure that
// widens staging liveness spills or halves occupancy: rounds 1,2,3,6).
template<int STAGE>
__global__ __launch_bounds__(256) void conv_mfma_kernel(
    const void* __restrict__ srcv,
    const _Float16* __restrict__ wp,      // [9][4][32co][8ci] fp16
    const float* __restrict__ bias,
    const float* __restrict__ scsh,       // [2*CH] (STAGE 2)
    _Float16* __restrict__ dst,
    float* __restrict__ partials)         // [64][NBLK] transposed
{
    __shared__ _Float16 ah[10368];        // [18y][4g][18x][8ci] = 20736 B
    __shared__ float red[4][64];

    const int tid = threadIdx.x;
    // XCD-aware swizzle: flat&7 -> image index, so each XCD rasters one image
    const int flat = blockIdx.x;
    const int bz = flat & 7;
    const int t  = flat >> 3;
    const int by = t >> 4, bx = t & 15;
    const int h0 = by*TILE - 1, w0 = bx*TILE - 1;

    // ---- stage + transform -> fp16 A-tile in LDS (sequential per-loc loop) ----
    #pragma unroll 1
    for (int loc = tid; loc < 324; loc += 256) {
        int y = loc / 18, x = loc - y*18;
        int gh = h0 + y, gw = w0 + x;
        if (gh < 0 || gh >= HWDIM || gw < 0 || gw >= HWDIM) {
            half8 z = {0,0,0,0,0,0,0,0};
            #pragma unroll
            for (int g = 0; g < 4; g++) *(half8*)(ah + ((y*4+g)*18 + x)*8) = z;
            continue;
        }
        float v[CH]; float n2 = 0.f;
        if (STAGE == 1) {
            const float* p = (const float*)srcv + ((size_t)bz*CH << 16) + gh*HWDIM + gw;
            #pragma unroll
            for (int c = 0; c < CH; c++) { float t0 = p[(size_t)c << 16]; v[c] = t0; n2 = fmaf(t0, t0, n2); }
            float n = fmaxf(sqrtf(n2), EPSF);
            float f = __fdividef(artanh_fast(n), n);
            #pragma unroll
            for (int c = 0; c < CH; c++) v[c] *= f;
        } else {
            const _Float16* p = (const _Float16*)srcv + (((size_t)bz << 16) + gh*HWDIM + gw)*CH;
            half8 raw[4];
            #pragma unroll
            for (int k = 0; k < 4; k++) raw[k] = *(const half8*)(p + 8*k);
            #pragma unroll
            for (int c = 0; c < CH; c++) {
                float t0 = fmaf((float)raw[c>>3][c&7], scsh[c], scsh[CH + c]);
                v[c] = t0; n2 = fmaf(t0, t0, n2);
            }
            float n = sqrtf(n2);
            float f = (n > R_CLAMP) ? __fdividef(R_CLAMP, n) : 1.0f;
            #pragma unroll
            for (int c = 0; c < CH; c++) v[c] = fmaxf(v[c]*f, 0.0f);
        }
        #pragma unroll
        for (int g = 0; g < 4; g++) {
            half8 hv;
            #pragma unroll
            for (int j = 0; j < 8; j++) hv[j] = (_Float16)v[g*8 + j];
            *(half8*)(ah + ((y*4+g)*18 + x)*8) = hv;
        }
    }
    __syncthreads();

    const int lane = tid & 63, wave = tid >> 6;
    const int xx = lane & 15, q = lane >> 4;

    floatx4 acc[4][2];
    #pragma unroll
    for (int i = 0; i < 4; i++) {
        acc[i][0] = (floatx4){0.f,0.f,0.f,0.f};
        acc[i][1] = (floatx4){0.f,0.f,0.f,0.f};
    }

    // ---- implicit GEMM, swapped operands: A = weights (m=co), B = acts (n=loc) ----
    // D[m=co=q*4+r(+16h)][n=loc x=xx] per loc-tile i (y = wave*4+i)
    __builtin_amdgcn_s_setprio(1);
    #pragma unroll
    for (int dx = 0; dx < 3; dx++) {
        half8 af[6];
        #pragma unroll
        for (int yy = 0; yy < 6; yy++)
            af[yy] = *(const half8*)(ah + (((wave*4+yy)*4 + q)*18 + xx + dx)*8);
        #pragma unroll
        for (int dy = 0; dy < 3; dy++) {
            const int o = dy*3 + dx;
            const _Float16* wb = wp + (size_t)((o*4 + q)*32)*8;
            half8 wf0 = *(const half8*)(wb + xx*8);          // A[m=xx][k=q*8+j], co 0..15
            half8 wf1 = *(const half8*)(wb + (xx+16)*8);     // co 16..31
            #pragma unroll
            for (int i = 0; i < 4; i++) {
                acc[i][0] = __builtin_amdgcn_mfma_f32_16x16x32_f16(wf0, af[i+dy], acc[i][0], 0,0,0);
                acc[i][1] = __builtin_amdgcn_mfma_f32_16x16x32_f16(wf1, af[i+dy], acc[i][1], 0,0,0);
            }
        }
    }
    __builtin_amdgcn_s_setprio(0);

    // ---- register epilogue: thread owns ch {q*4+r, q*4+r+16} of loc (y=wave*4+i, x=xx) ----
    float bs[8];
    #pragma unroll
    for (int r = 0; r < 4; r++) { bs[r] = bias[q*4+r]; bs[4+r] = bias[q*4+r+16]; }
    float sv[8], qv[8];
    #pragma unroll
    for (int k = 0; k < 8; k++) { sv[k] = 0.f; qv[k] = 0.f; }

    _Float16* dp = dst + (((size_t)bz << 16) + (size_t)(by*TILE)*HWDIM + bx*TILE + xx)*CH + q*4;

    #pragma unroll
    for (int i = 0; i < 4; i++) {
        float n2 = 0.f;
        #pragma unroll
        for (int r = 0; r < 4; r++) {
            acc[i][0][r] += bs[r];
            acc[i][1][r] += bs[4+r];
            n2 = fmaf(acc[i][0][r], acc[i][0][r], n2);
            n2 = fmaf(acc[i][1][r], acc[i][1][r], n2);
        }
        n2 += __shfl_xor(n2, 16, 64);
        n2 += __shfl_xor(n2, 32, 64);
        float nn = sqrtf(n2);
        float f = (nn > R_CLAMP) ? __fdividef(R_CLAMP, nn) : 1.0f;
        half4 o0, o1;
        #pragma unroll
        for (int r = 0; r < 4; r++) {
            float a0 = acc[i][0][r] * f;
            float a1 = acc[i][1][r] * f;
            sv[r]   += a0; qv[r]   = fmaf(a0, a0, qv[r]);
            sv[4+r] += a1; qv[4+r] = fmaf(a1, a1, qv[4+r]);
            o0[r] = (_Float16)a0; o1[r] = (_Float16)a1;
        }
        _Float16* a = dp + (size_t)(wave*4 + i)*HWDIM*CH;
        *(half4*)(a)      = o0;
        *(half4*)(a + 16) = o1;
    }

    // quad-reduce BN partials over the 16 xx-lanes
    #pragma unroll
    for (int k = 0; k < 8; k++) {
        #pragma unroll
        for (int m = 1; m < 16; m <<= 1) {
            sv[k] += __shfl_xor(sv[k], m, 64);
            qv[k] += __shfl_xor(qv[k], m, 64);
        }
    }
    if (xx == 0) {
        #pragma unroll
        for (int r = 0; r < 4; r++) {
            red[wave][q*4+r]        = sv[r];
            red[wave][16 + q*4+r]   = sv[4+r];
            red[wave][32 + q*4+r]   = qv[r];
            red[wave][48 + q*4+r]   = qv[4+r];
        }
    }
    __syncthreads();
    if (tid < 64) {
        float s = red[0][tid] + red[1][tid] + red[2][tid] + red[3][tid];
        partials[(size_t)tid*NBLK + flat] = s;
    }
}

__global__ __launch_bounds__(256) void finalize_kernel(
    const float* __restrict__ partials,
    const float* __restrict__ g, const float* __restrict__ beta,
    float* __restrict__ scsh)
{
    __shared__ float ss[256], sq[256];
    const int c = blockIdx.x;
    const int tid = threadIdx.x;
    float s = 0.f, q = 0.f;
    for (int b = tid; b < NBLK; b += 256) {
        s += partials[(size_t)c*NBLK + b];
        q += partials[(size_t)(CH + c)*NBLK + b];
    }
    ss[tid] = s; sq[tid] = q;
    __syncthreads();
    for (int st = 128; st > 0; st >>= 1) {
        if (tid < st) { ss[tid] += ss[tid+st]; sq[tid] += sq[tid+st]; }
        __syncthreads();
    }
    if (tid == 0) {
        const float NS = (float)NLOC;
        float mean = ss[0] / NS;
        float var = fmaxf(sq[0] / NS - mean*mean, 0.0f);
        float sc = g[c] / sqrtf(var + BN_EPS);
        scsh[c] = sc;
        scsh[CH + c] = beta[c] - mean*sc;
    }
}

// read t4 fp16 channel-minor; bn2+clampnorm+relu+expmap0+project; write fp32 NCHW
__global__ __launch_bounds__(256) void out_kernel(
    const _Float16* __restrict__ t4c, const float* __restrict__ scsh,
    float* __restrict__ out)
{
    __shared__ float outb[16*OST];
    const int w = threadIdx.x;
    const int h = blockIdx.x, n = blockIdx.y;
    const _Float16* p = t4c + (((size_t)n << 16) + (size_t)h*HWDIM + w)*CH;
    half8 raw[4];
    #pragma unroll
    for (int k = 0; k < 4; k++) raw[k] = *(const half8*)(p + 8*k);
    float u[CH]; float n2 = 0.f;
    #pragma unroll
    for (int c = 0; c < CH; c++) {
        float t = fmaf((float)raw[c>>3][c&7], scsh[c], scsh[CH+c]);
        u[c] = t; n2 = fmaf(t, t, n2);
    }
    float nn = sqrtf(n2);
    float f = (nn > R_CLAMP) ? __fdividef(R_CLAMP, nn) : 1.0f;
    float r2 = 0.f;
    #pragma unroll
    for (int c = 0; c < CH; c++) { float r = fmaxf(u[c]*f, 0.0f); u[c] = r; r2 = fmaf(r, r, r2); }
    float rn = fmaxf(sqrtf(r2), EPSF);
    // tanh(rn) = (e^{2rn}-1)/(e^{2rn}+1); rn <= ~4.95 so e^{2rn} <= ~2e4, safe in fp32
    float a = __expf(2.0f * rn);
    float th = __fdividef(a - 1.0f, a + 1.0f);
    float s = __fdividef(fminf(th, MAXN), rn);
    #pragma unroll
    for (int c = 0; c < CH; c++) u[c] *= s;

    #pragma unroll
    for (int hf = 0; hf < 2; hf++) {
        if (hf) __syncthreads();
        #pragma unroll
        for (int c = 0; c < 16; c++) outb[c*OST + w] = u[hf*16 + c];
        __syncthreads();
        int co = threadIdx.x >> 4, seg = threadIdx.x & 15;
        const float* row = outb + co*OST + seg*16;
        float* gp = out + ((size_t)(n*CH + hf*16 + co) << 16) + (size_t)h*HWDIM + seg*16;
        #pragma unroll
        for (int k = 0; k < 4; k++) *(floatx4*)(gp + 4*k) = *(const floatx4*)(row + 4*k);
    }
}

extern "C" void kernel_launch(void* const* d_in, const int* in_sizes, int n_in,
                              void* d_out, int out_size, void* d_ws, size_t ws_size,
                              hipStream_t stream)
{
    const float* x   = (const float*)d_in[0];
    const float* w1  = (const float*)d_in[1];
    const float* b1  = (const float*)d_in[2];
    const float* g1  = (const float*)d_in[3];
    const float* be1 = (const float*)d_in[4];
    const float* w2  = (const float*)d_in[5];
    const float* b2  = (const float*)d_in[6];
    const float* g2  = (const float*)d_in[7];
    const float* be2 = (const float*)d_in[8];
    float* outf = (float*)d_out;

    char* ws = (char*)d_ws;
    _Float16* wp1   = (_Float16*)ws;                     // 9216 halves
    _Float16* wp2   = wp1 + 9216;                        // 9216 halves -> 36864 B
    float* partials = (float*)(ws + 36864);              // [64][2048] floats
    float* scsh1    = (float*)(ws + 36864 + 524288);     // 64
    float* scsh2    = scsh1 + 64;                        // 64
    _Float16* t1c   = (_Float16*)(scsh2 + 64);           // 16.7M halves (32 MB)
    _Float16* t4c   = t1c + (size_t)NLOC*CH;             // 16.7M halves (32 MB)

    wprep_kernel<<<72, 256, 0, stream>>>(w1, w2, wp1, wp2);

    conv_mfma_kernel<1><<<NBLK, 256, 0, stream>>>(x, wp1, b1, scsh1, t1c, partials);
    finalize_kernel<<<32, 256, 0, stream>>>(partials, g1, be1, scsh1);
    conv_mfma_kernel<2><<<NBLK, 256, 0, stream>>>(t1c, wp2, b2, scsh1, t4c, partials);
    finalize_kernel<<<32, 256, 0, stream>>>(partials, g2, be2, scsh2);
    out_kernel<<<dim3(HWDIM, NB), 256, 0, stream>>>(t4c, scsh2, outf);
}